// Round 6
// baseline (907.401 us; speedup 1.0000x reference)
//
#include <hip/hip_runtime.h>
#include <math.h>

#define H    24
#define Dh   128
#define LIMG 2048
#define LIP  512
#define DM   3072
#define DIP  1280
#define LK   2560
#define EPSF 1e-6f
#define SM_SCALE 0.08838834764831845f  // 1/sqrt(128)

typedef __attribute__((ext_vector_type(8))) short bf16x8;
typedef __attribute__((ext_vector_type(4))) float f32x4;
typedef const unsigned int __attribute__((address_space(1))) gu32;
typedef unsigned int __attribute__((address_space(3))) lu32;
typedef unsigned short u16;

static __device__ __forceinline__ u16 f2bf(float x) {
  union { float f; unsigned u; } v; v.f = x;
  unsigned r = v.u + 0x7fffu + ((v.u >> 16) & 1u);  // RNE
  return (u16)(r >> 16);
}

static __device__ __forceinline__ float bf2f(u16 x) {
  union { unsigned u; float f; } v; v.u = ((unsigned)x) << 16;
  return v.f;
}

// ---------------- Kernel 1: e = silu(t_emb) @ w_ada^T + b_ada ----------------
__global__ __launch_bounds__(256) void ada_kernel(
    const float* __restrict__ t_emb, const float* __restrict__ w_ada,
    const float* __restrict__ b_ada, float* __restrict__ e) {
  int j = blockIdx.x;
  int tid = threadIdx.x;
  const float* wrow = w_ada + (long)j * DIP;
  float acc = 0.f;
  for (int k = tid; k < DIP; k += 256) {
    float t = t_emb[k];
    acc += (t / (1.f + expf(-t))) * wrow[k];
  }
#pragma unroll
  for (int m = 1; m < 64; m <<= 1) acc += __shfl_xor(acc, m, 64);
  __shared__ float red[4];
  if ((tid & 63) == 0) red[tid >> 6] = acc;
  __syncthreads();
  if (tid == 0) e[j] = red[0] + red[1] + red[2] + red[3] + b_ada[j];
}

// ---------------- Kernel 2: AdaLayerNorm -> ip_norm (bf16) ----------------
__global__ __launch_bounds__(256) void adaln_kernel(
    const float* __restrict__ x, const float* __restrict__ e,
    u16* __restrict__ ipn_b) {
  int r = blockIdx.x;
  int tid = threadIdx.x;
  const float* xr = x + (long)r * DIP;
  float v[5];
  float s = 0.f, ss = 0.f;
#pragma unroll
  for (int i = 0; i < 5; i++) {
    v[i] = xr[tid + i * 256];
    s += v[i];
    ss += v[i] * v[i];
  }
#pragma unroll
  for (int m = 1; m < 64; m <<= 1) {
    s += __shfl_xor(s, m, 64);
    ss += __shfl_xor(ss, m, 64);
  }
  __shared__ float rs_[4], rss_[4];
  if ((tid & 63) == 0) { rs_[tid >> 6] = s; rss_[tid >> 6] = ss; }
  __syncthreads();
  s = rs_[0] + rs_[1] + rs_[2] + rs_[3];
  ss = rss_[0] + rss_[1] + rss_[2] + rss_[3];
  float mu = s * (1.f / DIP);
  float var = ss * (1.f / DIP) - mu * mu;
  float rstd = rsqrtf(var + EPSF);
  u16* outr = ipn_b + (long)r * DIP;
#pragma unroll
  for (int i = 0; i < 5; i++) {
    int c = tid + i * 256;
    outr[c] = f2bf((v[i] - mu) * rstd * (1.f + e[DIP + c]) + e[c]);
  }
}

// ---------------- Kernel 3: img K (RMS) -> Kb bf16, img V -> Vt bf16 (transposed) --
__global__ __launch_bounds__(256) void prep_kernel(
    const float* __restrict__ k_in, const float* __restrict__ v_in,
    const float* __restrict__ g_k,
    u16* __restrict__ Kb, u16* __restrict__ Vt) {
  __shared__ u16 Vls[128][33];
  int h = blockIdx.y, l0 = blockIdx.x * 32;
  int tid = threadIdx.x;
  int r = tid >> 3, c = tid & 7;
  const float* ksrc = k_in + (long)(l0 + r) * DM + h * Dh + c * 16;
  const float* vsrc = v_in + (long)(l0 + r) * DM + h * Dh + c * 16;
  float kv[16], vv[16];
  float ssq = 0.f;
#pragma unroll
  for (int i = 0; i < 4; i++) {
    float4 a = *(const float4*)(ksrc + i * 4);
    float4 b = *(const float4*)(vsrc + i * 4);
    kv[i*4+0]=a.x; kv[i*4+1]=a.y; kv[i*4+2]=a.z; kv[i*4+3]=a.w;
    vv[i*4+0]=b.x; vv[i*4+1]=b.y; vv[i*4+2]=b.z; vv[i*4+3]=b.w;
    ssq += a.x*a.x + a.y*a.y + a.z*a.z + a.w*a.w;
  }
  ssq += __shfl_xor(ssq, 1, 8);
  ssq += __shfl_xor(ssq, 2, 8);
  ssq += __shfl_xor(ssq, 4, 8);
  float rstd = rsqrtf(ssq * (1.f / Dh) + EPSF);
  u16 kb[16];
#pragma unroll
  for (int i = 0; i < 16; i++) kb[i] = f2bf(kv[i] * rstd * g_k[c * 16 + i]);
  u16* kdst = Kb + ((long)h * LK + l0 + r) * Dh + c * 16;
  *(uint4*)(kdst) = *(uint4*)(kb);
  *(uint4*)(kdst + 8) = *(uint4*)(kb + 8);
#pragma unroll
  for (int i = 0; i < 16; i++) Vls[c * 16 + i][r] = f2bf(vv[i]);
  __syncthreads();
  int d = tid >> 1, half = (tid & 1) * 16;
  u16 ov[16];
#pragma unroll
  for (int j = 0; j < 16; j++) ov[j] = Vls[d][half + j];
  u16* vdst = Vt + ((long)h * Dh + d) * LK + l0 + half;
  *(uint4*)(vdst) = *(uint4*)(ov);
  *(uint4*)(vdst + 8) = *(uint4*)(ov + 8);
}

// ---------------- Kernel 4 (DIAGNOSTIC): brute-force scalar ip projections --------
// Block = (4 ip rows, 1 head), 256 threads. Thread t<128: ip_key col t of the head;
// t>=128: ip_value col t-128. Every index is literally the math. LDS broadcast only.
__global__ __launch_bounds__(256) void simple_proj(
    const u16* __restrict__ ipn_b, const float* __restrict__ Wk,
    const float* __restrict__ Wv, const float* __restrict__ g_ipk,
    u16* __restrict__ Kb, u16* __restrict__ Vt) {
  __shared__ float xs[4][DIP];    // 20 KB
  __shared__ float kvs[4][128];   // 2 KB
  int l0 = blockIdx.x * 4, h = blockIdx.y, tid = threadIdx.x;
  for (int i = tid; i < 4 * DIP; i += 256) {
    int r = i / DIP, c = i - r * DIP;
    xs[r][c] = bf2f(ipn_b[(long)(l0 + r) * DIP + c]);
  }
  __syncthreads();
  int t = tid & 127;
  bool isK = tid < 128;
  const float* wrow = (isK ? Wk : Wv) + (long)(h * Dh + t) * DIP;
  float acc[4] = {0.f, 0.f, 0.f, 0.f};
  for (int k = 0; k < DIP; k += 4) {
    float4 w4 = *(const float4*)(wrow + k);
#pragma unroll
    for (int r = 0; r < 4; r++)
      acc[r] += xs[r][k] * w4.x + xs[r][k+1] * w4.y +
                xs[r][k+2] * w4.z + xs[r][k+3] * w4.w;
  }
  if (isK) {
#pragma unroll
    for (int r = 0; r < 4; r++) kvs[r][t] = acc[r];
  }
  __syncthreads();
  if (isK) {
#pragma unroll 1
    for (int r = 0; r < 4; r++) {
      float ssq = 0.f;
      for (int i = 0; i < 128; i++) { float x = kvs[r][i]; ssq += x * x; }
      float rstd = rsqrtf(ssq * (1.f / Dh) + EPSF);
      Kb[((long)h * LK + LIMG + l0 + r) * Dh + t] = f2bf(acc[r] * rstd * g_ipk[t]);
    }
  } else {
#pragma unroll
    for (int r = 0; r < 4; r++)
      Vt[((long)h * Dh + t) * LK + LIMG + l0 + r] = f2bf(acc[r]);
  }
}

// ---------------- Kernel 5: MFMA flash attention (round-2 verified version) --------
__global__ __launch_bounds__(256, 4) void flash_kernel(
    const float* __restrict__ q_in, const float* __restrict__ g_q,
    const u16* __restrict__ Kb, const u16* __restrict__ Vt,
    float* __restrict__ out) {
  __shared__ __align__(16) unsigned char lds[8192 + 8192 + 5120];
  u16* Ks = (u16*)lds;            // [32 rows][16 granules, XOR-swizzled]
  u16* Vs = (u16*)(lds + 8192);   // [128 d][4 granules]
  u16* Ps = (u16*)(lds + 16384);  // per wave: 16 rows x 40 ushorts
  int tid = threadIdx.x;
  int w = tid >> 6, lid = tid & 63;
  int m = lid & 15, quad = lid >> 4;
  int h = blockIdx.y;
  int q0 = blockIdx.x * 64;
  int qrow = q0 + w * 16 + m;

  bf16x8 aq[4];
  {
    float qf[4][8];
    float ssq = 0.f;
    const float* qsrc = q_in + (long)qrow * DM + h * Dh + quad * 8;
#pragma unroll
    for (int ks = 0; ks < 4; ks++) {
      float4 a = *(const float4*)(qsrc + ks * 32);
      float4 b = *(const float4*)(qsrc + ks * 32 + 4);
      qf[ks][0]=a.x; qf[ks][1]=a.y; qf[ks][2]=a.z; qf[ks][3]=a.w;
      qf[ks][4]=b.x; qf[ks][5]=b.y; qf[ks][6]=b.z; qf[ks][7]=b.w;
      ssq += a.x*a.x + a.y*a.y + a.z*a.z + a.w*a.w;
      ssq += b.x*b.x + b.y*b.y + b.z*b.z + b.w*b.w;
    }
    ssq += __shfl_xor(ssq, 16, 64);
    ssq += __shfl_xor(ssq, 32, 64);
    float rstd = rsqrtf(ssq * (1.f / Dh) + EPSF);
    const float* gq = g_q + quad * 8;
#pragma unroll
    for (int ks = 0; ks < 4; ks++) {
      float4 ga = *(const float4*)(gq + ks * 32);
      float4 gb = *(const float4*)(gq + ks * 32 + 4);
      float gg[8] = {ga.x, ga.y, ga.z, ga.w, gb.x, gb.y, gb.z, gb.w};
#pragma unroll
      for (int j = 0; j < 8; j++)
        aq[ks][j] = (short)f2bf(qf[ks][j] * rstd * gg[j]);
    }
  }

  const u16* KbH = Kb + (long)h * LK * Dh;
  const u16* VtH = Vt + (long)h * Dh * LK;
  u16* Pw = Ps + w * (16 * 40);

  f32x4 acc_o[8];
#pragma unroll
  for (int i = 0; i < 8; i++) acc_o[i] = (f32x4){0.f, 0.f, 0.f, 0.f};
  float mrun[4] = {-INFINITY, -INFINITY, -INFINITY, -INFINITY};
  float lrun[4] = {0.f, 0.f, 0.f, 0.f};

#pragma unroll 1
  for (int j0 = 0; j0 < LK; j0 += 32) {
    __syncthreads();
    {
      int sbase = w * 128;
#pragma unroll
      for (int is = 0; is < 2; is++) {
        int s = sbase + is * 64 + lid;
        int r = s >> 4, cc = s & 15;
        int c = cc ^ (r & 15);
        const u16* g = KbH + (long)(j0 + r) * Dh + c * 8;
        __builtin_amdgcn_global_load_lds((gu32*)g, (lu32*)(Ks + (sbase + is * 64) * 8),
                                         16, 0, 0);
      }
#pragma unroll
      for (int is = 0; is < 2; is++) {
        int s = sbase + is * 64 + lid;
        int d = s >> 2, cc = s & 3;
        const u16* g = VtH + (long)d * LK + j0 + cc * 8;
        __builtin_amdgcn_global_load_lds((gu32*)g, (lu32*)(Vs + (sbase + is * 64) * 8),
                                         16, 0, 0);
      }
    }
    __syncthreads();

    f32x4 sc[2];
    sc[0] = (f32x4){0.f, 0.f, 0.f, 0.f};
    sc[1] = (f32x4){0.f, 0.f, 0.f, 0.f};
#pragma unroll
    for (int t = 0; t < 2; t++)
#pragma unroll
      for (int ks = 0; ks < 4; ks++) {
        int rr = t * 16 + m;
        int g = (ks * 4 + quad) ^ m;
        bf16x8 bk = *(const bf16x8*)(Ks + rr * 128 + g * 8);
        sc[t] = __builtin_amdgcn_mfma_f32_16x16x32_bf16(aq[ks], bk, sc[t], 0, 0, 0);
      }

    float mx[4], al[4], ps0[4], ps1[4];
#pragma unroll
    for (int r = 0; r < 4; r++) {
      float v0 = sc[0][r] * SM_SCALE, v1 = sc[1][r] * SM_SCALE;
      ps0[r] = v0; ps1[r] = v1;
      float mm = fmaxf(v0, v1);
      mm = fmaxf(mm, __shfl_xor(mm, 1, 16));
      mm = fmaxf(mm, __shfl_xor(mm, 2, 16));
      mm = fmaxf(mm, __shfl_xor(mm, 4, 16));
      mm = fmaxf(mm, __shfl_xor(mm, 8, 16));
      mx[r] = mm;
    }
#pragma unroll
    for (int r = 0; r < 4; r++) {
      float mn = fmaxf(mrun[r], mx[r]);
      al[r] = __expf(mrun[r] - mn);
      mrun[r] = mn;
      float p0 = __expf(ps0[r] - mn), p1 = __expf(ps1[r] - mn);
      ps0[r] = p0; ps1[r] = p1;
      float s2 = p0 + p1;
      s2 += __shfl_xor(s2, 1, 16);
      s2 += __shfl_xor(s2, 2, 16);
      s2 += __shfl_xor(s2, 4, 16);
      s2 += __shfl_xor(s2, 8, 16);
      lrun[r] = lrun[r] * al[r] + s2;
    }
#pragma unroll
    for (int r = 0; r < 4; r++) {
      Pw[(quad * 4 + r) * 40 + m] = f2bf(ps0[r]);
      Pw[(quad * 4 + r) * 40 + 16 + m] = f2bf(ps1[r]);
    }
    __threadfence_block();
    bf16x8 ap = *(const bf16x8*)(Pw + m * 40 + quad * 8);
#pragma unroll
    for (int dt = 0; dt < 8; dt++) {
      acc_o[dt][0] *= al[0]; acc_o[dt][1] *= al[1];
      acc_o[dt][2] *= al[2]; acc_o[dt][3] *= al[3];
    }
#pragma unroll
    for (int dt = 0; dt < 8; dt++) {
      bf16x8 bv = *(const bf16x8*)(Vs + (dt * 16 + m) * 32 + quad * 8);
      acc_o[dt] = __builtin_amdgcn_mfma_f32_16x16x32_bf16(ap, bv, acc_o[dt], 0, 0, 0);
    }
  }

  float il[4] = {1.f / lrun[0], 1.f / lrun[1], 1.f / lrun[2], 1.f / lrun[3]};
#pragma unroll
  for (int dt = 0; dt < 8; dt++)
#pragma unroll
    for (int r = 0; r < 4; r++)
      out[(long)(q0 + w * 16 + quad * 4 + r) * DM + h * Dh + dt * 16 + m] =
          acc_o[dt][r] * il[r];
}

// ---------------- launch ----------------
extern "C" void kernel_launch(void* const* d_in, const int* in_sizes, int n_in,
                              void* d_out, int out_size, void* d_ws, size_t ws_size,
                              hipStream_t stream) {
  const float* ip_hidden = (const float*)d_in[0];
  const float* img_q     = (const float*)d_in[1];
  const float* img_k     = (const float*)d_in[2];
  const float* img_v     = (const float*)d_in[3];
  const float* t_emb     = (const float*)d_in[4];
  const float* w_ada     = (const float*)d_in[5];
  const float* b_ada     = (const float*)d_in[6];
  const float* w_k_ip    = (const float*)d_in[7];
  const float* w_v_ip    = (const float*)d_in[8];
  const float* g_q       = (const float*)d_in[9];
  const float* g_k       = (const float*)d_in[10];
  const float* g_ipk     = (const float*)d_in[11];

  float* ws = (float*)d_ws;
  float* e  = ws;                                   // 2560 used (4096 reserved)
  u16* ipn_b = (u16*)(ws + 4096);                   // 512*1280 bf16
  u16* Kb = ipn_b + (size_t)LIP * DIP;              // 24*2560*128 bf16
  u16* Vt = Kb + (size_t)H * LK * Dh;               // 24*128*2560 bf16
  float* out = (float*)d_out;

  ada_kernel<<<2 * DIP, 256, 0, stream>>>(t_emb, w_ada, b_ada, e);
  adaln_kernel<<<LIP, 256, 0, stream>>>(ip_hidden, e, ipn_b);
  prep_kernel<<<dim3(LIMG / 32, H), 256, 0, stream>>>(img_k, img_v, g_k, Kb, Vt);
  simple_proj<<<dim3(LIP / 4, H), 256, 0, stream>>>(ipn_b, w_k_ip, w_v_ip, g_ipk, Kb, Vt);
  flash_kernel<<<dim3(LIMG / 64, H), 256, 0, stream>>>(img_q, g_q, Kb, Vt, out);
}